// Round 1
// baseline (2410.459 us; speedup 1.0000x reference)
//
#include <hip/hip_runtime.h>
#include <math.h>

#define BB 32
#define CIN 256
#define COUT 256
#define SP 64
#define SPP (SP*SP)      // 4096
#define SDIM 256         // half of style dim

constexpr float LIN_SCALE  = 0.0625f;                 // 1/sqrt(256)
constexpr float CONV_SCALE = 0.020833333333333332f;   // 1/sqrt(2304)
constexpr float EPS = 1e-6f;

// ws layout (floats):
// [0      , 8192  ) style[b][ci]
// [8192   , 16384 ) demod[b][co]
// [16384  , 81920 ) wsq[co][ci]
// [81920  , 212992) sp[b][p]
// [212992 , 213024) dsp[b]
#define WS_STYLE 0
#define WS_DEMOD 8192
#define WS_WSQ   16384
#define WS_SP    81920
#define WS_DSP   212992

// ---------------- prep kernels ----------------

__global__ void k_wsq(const float* __restrict__ weight, float* __restrict__ wsq) {
    int co = blockIdx.x, ci = threadIdx.x;
    const float* wp = weight + (co * CIN + ci) * 9;
    float s = 0.f;
#pragma unroll
    for (int t = 0; t < 9; t++) { float v = wp[t]; s += v * v; }
    wsq[co * CIN + ci] = s;
}

__global__ void k_style(const float* __restrict__ style_in,
                        const float* __restrict__ mod_w,
                        const float* __restrict__ mod_b,
                        const float* __restrict__ wsq,
                        float* __restrict__ style,
                        float* __restrict__ demod) {
    __shared__ float s_in[SDIM];
    __shared__ float s2[CIN];
    int b = blockIdx.x, t = threadIdx.x;
    s_in[t] = style_in[b * 512 + t];          // channel half = first 256
    __syncthreads();
    const float* mw = mod_w + t * SDIM;       // row ci = t
    float acc = 0.f;
    for (int k = 0; k < SDIM; k++) acc += s_in[k] * mw[k];
    float st = acc * LIN_SCALE + mod_b[t];
    style[b * CIN + t] = st;
    s2[t] = st * st;
    __syncthreads();
    const float* wq = wsq + t * CIN;          // row co = t
    float d = 0.f;
    for (int ci = 0; ci < CIN; ci++) d += wq[ci] * s2[ci];
    demod[b * COUT + t] = rsqrtf(CONV_SCALE * CONV_SCALE * d + EPS);
}

__global__ void k_spatial(const float* __restrict__ style_in,
                          const float* __restrict__ sp_w,
                          const float* __restrict__ sp_b,
                          float* __restrict__ sp,
                          float* __restrict__ dsp) {
    __shared__ float s_in[SDIM];
    __shared__ float red[256];
    int b = blockIdx.x, t = threadIdx.x;
    s_in[t] = style_in[b * 512 + 256 + t];    // spatial half = last 256
    __syncthreads();
    float ss = 0.f;
    for (int i = 0; i < 16; i++) {
        int p = i * 256 + t;
        const float* wr = sp_w + p * SDIM;
        float acc = 0.f;
        for (int k = 0; k < SDIM; k++) acc += s_in[k] * wr[k];
        float v = acc * LIN_SCALE + sp_b[p];
        sp[b * SPP + p] = v;
        ss += v * v;
    }
    red[t] = ss; __syncthreads();
    for (int o = 128; o > 0; o >>= 1) { if (t < o) red[t] += red[t + o]; __syncthreads(); }
    if (t == 0) dsp[b] = sqrtf((float)SPP / red[0] + EPS);
}

// ---------------- conv kernel (fp32 baseline) ----------------
// block = 256 threads; per block: one b, 16 output channels, 32x32 spatial tile
// grid = 32 * 16 * 4 = 2048 blocks

#define COTILE 16
#define TS 32
#define HALO 34
#define XS 36    // padded LDS row stride (16B aligned rows)

__global__ __launch_bounds__(256) void k_conv(
    const float* __restrict__ x, const float* __restrict__ weight,
    const float* __restrict__ style, const float* __restrict__ demod,
    const float* __restrict__ sp, const float* __restrict__ dsp,
    float* __restrict__ out) {
    __shared__ float xt[HALO * XS];
    __shared__ float wl[COTILE * 12];
    __shared__ float dml[COTILE];

    int bid  = blockIdx.x;
    int tile = bid & 3;
    int cot  = (bid >> 2) & 15;
    int b    = bid >> 6;
    int h0 = (tile >> 1) * TS, w0 = (tile & 1) * TS;
    int t  = threadIdx.x;
    int r  = t >> 3;           // 0..31 local row
    int cb = (t & 7) * 4;      // 0..28 local col base

    if (t < COTILE) dml[t] = demod[b * COUT + cot * COTILE + t];

    float acc[COTILE][4];
#pragma unroll
    for (int co = 0; co < COTILE; co++)
#pragma unroll
        for (int c = 0; c < 4; c++) acc[co][c] = 0.f;

    const float* xb = x + (size_t)b * CIN * SPP;
    const float* stb = style + b * CIN;

    for (int ci = 0; ci < CIN; ci++) {
        __syncthreads();
        // stage x tile (with halo, zero-padded)
        const float* xc = xb + ci * SPP;
        for (int idx = t; idx < HALO * HALO; idx += 256) {
            int i = idx / HALO, j = idx - i * HALO;
            int h = h0 + i - 1, w = w0 + j - 1;
            float v = 0.f;
            if ((unsigned)h < SP && (unsigned)w < SP) v = xc[h * SP + w];
            xt[i * XS + j] = v;
        }
        // stage modulated weights for this ci
        if (t < COTILE * 9) {
            int co = t / 9, tap = t - co * 9;
            float wv = weight[((cot * COTILE + co) * CIN + ci) * 9 + tap];
            wl[co * 12 + tap] = wv * (CONV_SCALE * stb[ci]) * dml[co];
        }
        __syncthreads();

        float xv[3][6];
#pragma unroll
        for (int dh = 0; dh < 3; dh++)
#pragma unroll
            for (int jj = 0; jj < 6; jj++)
                xv[dh][jj] = xt[(r + dh) * XS + cb + jj];

#pragma unroll
        for (int co = 0; co < COTILE; co++) {
            float w9[9];
#pragma unroll
            for (int q = 0; q < 9; q++) w9[q] = wl[co * 12 + q];
#pragma unroll
            for (int c = 0; c < 4; c++) {
                float a = acc[co][c];
#pragma unroll
                for (int dh = 0; dh < 3; dh++)
#pragma unroll
                    for (int dw = 0; dw < 3; dw++)
                        a += w9[dh * 3 + dw] * xv[dh][c + dw];
                acc[co][c] = a;
            }
        }
    }

    // epilogue: spatial modulation + store
    float dspb = dsp[b];
    int hh = h0 + r, ww = w0 + cb;
    const float* spb = sp + b * SPP + hh * SP + ww;
    float m[4];
#pragma unroll
    for (int c = 0; c < 4; c++) m[c] = spb[c] * dspb;
#pragma unroll
    for (int co = 0; co < COTILE; co++) {
        float4 v = make_float4(acc[co][0] * m[0], acc[co][1] * m[1],
                               acc[co][2] * m[2], acc[co][3] * m[3]);
        *(float4*)&out[(size_t)((b * COUT + cot * COTILE + co) * SPP) + hh * SP + ww] = v;
    }
}

// ---------------- launcher ----------------

extern "C" void kernel_launch(void* const* d_in, const int* in_sizes, int n_in,
                              void* d_out, int out_size, void* d_ws, size_t ws_size,
                              hipStream_t stream) {
    const float* x        = (const float*)d_in[0];
    const float* style_in = (const float*)d_in[1];
    const float* weight   = (const float*)d_in[2];
    const float* mod_w    = (const float*)d_in[3];
    const float* mod_b    = (const float*)d_in[4];
    const float* sp_w     = (const float*)d_in[5];
    const float* sp_b     = (const float*)d_in[6];
    float* out = (float*)d_out;
    float* ws  = (float*)d_ws;

    float* style = ws + WS_STYLE;
    float* demod = ws + WS_DEMOD;
    float* wsq   = ws + WS_WSQ;
    float* sp    = ws + WS_SP;
    float* dsp   = ws + WS_DSP;

    hipLaunchKernelGGL(k_wsq, dim3(COUT), dim3(CIN), 0, stream, weight, wsq);
    hipLaunchKernelGGL(k_style, dim3(BB), dim3(256), 0, stream,
                       style_in, mod_w, mod_b, wsq, style, demod);
    hipLaunchKernelGGL(k_spatial, dim3(BB), dim3(256), 0, stream,
                       style_in, sp_w, sp_b, sp, dsp);
    hipLaunchKernelGGL(k_conv, dim3(BB * 16 * 4), dim3(256), 0, stream,
                       x, weight, style, demod, sp, dsp, out);
}

// Round 3
// 592.207 us; speedup vs baseline: 4.0703x; 4.0703x over previous
//
#include <hip/hip_runtime.h>
#include <math.h>

typedef short short8 __attribute__((ext_vector_type(8)));
typedef float f32x4 __attribute__((ext_vector_type(4)));

#define BB 32
#define CIN 256
#define COUT 256
#define SPD 64
#define SPP 4096
#define SDIM 256

constexpr float LIN_SCALE  = 0.0625f;                 // 1/sqrt(256)
constexpr float CONV_SCALE = 0.020833333333333332f;   // 1/sqrt(2304)
constexpr float EPS = 1e-6f;

// ---- ws byte-offset layout ----
#define WSB_STYLE   0ULL
#define WSB_DEMOD   32768ULL
#define WSB_WSQ     65536ULL
#define WSB_SP      327680ULL
#define WSB_DSP     851968ULL
#define WSB_ZERO    852096ULL      // 1 KiB of zeros
#define WSB_WT2     860160ULL      // 1,179,648 B bf16 weights [tap][co][ci]
#define WSB_XST     2097152ULL     // 67,108,864 B bf16 xs_t [b][p][ci]
#define WS_NEED     (WSB_XST + 67108864ULL)

__device__ inline unsigned short f2bf(float f) {
    unsigned u = __builtin_bit_cast(unsigned, f);
    u = (u + 0x7fffu + ((u >> 16) & 1u)) >> 16;   // RNE
    return (unsigned short)u;
}

// ---------------- prep kernels ----------------

__global__ void k_zero(unsigned* __restrict__ p) {
    p[threadIdx.x] = 0u;   // 256 u32 = 1 KiB
}

__global__ void k_wsq(const float* __restrict__ weight, float* __restrict__ wsq) {
    int co = blockIdx.x, ci = threadIdx.x;
    const float* wp = weight + (co * CIN + ci) * 9;
    float s = 0.f;
#pragma unroll
    for (int t = 0; t < 9; t++) { float v = wp[t]; s += v * v; }
    wsq[co * CIN + ci] = s;
}

__global__ void k_style(const float* __restrict__ style_in,
                        const float* __restrict__ mod_w,
                        const float* __restrict__ mod_b,
                        const float* __restrict__ wsq,
                        float* __restrict__ style,
                        float* __restrict__ demod) {
    __shared__ float s_in[SDIM];
    __shared__ float s2[CIN];
    int b = blockIdx.x, t = threadIdx.x;
    s_in[t] = style_in[b * 512 + t];
    __syncthreads();
    const float* mw = mod_w + t * SDIM;
    float acc = 0.f;
    for (int k = 0; k < SDIM; k++) acc += s_in[k] * mw[k];
    float st = acc * LIN_SCALE + mod_b[t];
    style[b * CIN + t] = st;
    s2[t] = st * st;
    __syncthreads();
    const float* wq = wsq + t * CIN;
    float d = 0.f;
    for (int ci = 0; ci < CIN; ci++) d += wq[ci] * s2[ci];
    demod[b * COUT + t] = rsqrtf(CONV_SCALE * CONV_SCALE * d + EPS);
}

__global__ void k_spatial(const float* __restrict__ style_in,
                          const float* __restrict__ sp_w,
                          const float* __restrict__ sp_b,
                          float* __restrict__ sp,
                          float* __restrict__ dsp) {
    __shared__ float s_in[SDIM];
    __shared__ float red[256];
    int b = blockIdx.x, t = threadIdx.x;
    s_in[t] = style_in[b * 512 + 256 + t];
    __syncthreads();
    float ss = 0.f;
    for (int i = 0; i < 16; i++) {
        int p = i * 256 + t;
        const float* wr = sp_w + p * SDIM;
        float acc = 0.f;
        for (int k = 0; k < SDIM; k++) acc += s_in[k] * wr[k];
        float v = acc * LIN_SCALE + sp_b[p];
        sp[b * SPP + p] = v;
        ss += v * v;
    }
    red[t] = ss; __syncthreads();
    for (int o = 128; o > 0; o >>= 1) { if (t < o) red[t] += red[t + o]; __syncthreads(); }
    if (t == 0) dsp[b] = sqrtf((float)SPP / red[0] + EPS);
}

// weight [co][ci][tap] fp32 -> wt2[tap][co][ci] bf16 (raw, unscaled)
__global__ void k_wt(const float* __restrict__ weight, unsigned short* __restrict__ wt2) {
    int idx = blockIdx.x * 256 + threadIdx.x;   // grid 2304 -> 589824
    int tap = idx >> 16;
    int r = idx & 65535;
    int co = r >> 8, ci = r & 255;
    wt2[idx] = f2bf(weight[(co * 256 + ci) * 9 + tap]);
}

// x [b][ci][p] fp32 -> xs_t[b][p][ci] bf16, scaled by style[b][ci]
__global__ void k_xt(const float* __restrict__ x, const float* __restrict__ style,
                     unsigned short* __restrict__ xst) {
    int b = blockIdx.x >> 4, pc = blockIdx.x & 15;   // 16 chunks of 256 p
    int t = threadIdx.x;                              // 0..127, ci pair = 2t
    int ci = t * 2;
    float s0 = style[b * 256 + ci], s1 = style[b * 256 + ci + 1];
    const float* xa = x + ((size_t)(b * 256 + ci)) * SPP + pc * 256;
    const float* xc = xa + SPP;
    unsigned* o = (unsigned*)(xst + ((size_t)b * SPP + pc * 256) * 256);
    for (int j = 0; j < 64; j++) {
        float4 a4 = *(const float4*)(xa + j * 4);
        float4 b4 = *(const float4*)(xc + j * 4);
        o[(j * 4 + 0) * 128 + t] = (unsigned)f2bf(a4.x * s0) | ((unsigned)f2bf(b4.x * s1) << 16);
        o[(j * 4 + 1) * 128 + t] = (unsigned)f2bf(a4.y * s0) | ((unsigned)f2bf(b4.y * s1) << 16);
        o[(j * 4 + 2) * 128 + t] = (unsigned)f2bf(a4.z * s0) | ((unsigned)f2bf(b4.z * s1) << 16);
        o[(j * 4 + 3) * 128 + t] = (unsigned)f2bf(a4.w * s0) | ((unsigned)f2bf(b4.w * s1) << 16);
    }
}

// ---------------- MFMA conv kernel ----------------
// grid 2048: bid -> rt(32 row-pairs) | mt(2 co-halves) | b(32)
// block 256 = 4 waves: wave w: mw=w&1 (64-co half), rr=w>>1 (row in pair)
// LDS x-tile per K-chunk: 264 slots (4 rows x 66 cols) x 128B (64 ci bf16)

__global__ __launch_bounds__(256, 2) void k_conv_mfma(
    const unsigned short* __restrict__ xst,
    const unsigned short* __restrict__ wt2,
    const float* __restrict__ demod,
    const float* __restrict__ sp,
    const float* __restrict__ dsp,
    const unsigned short* __restrict__ zeropad,
    float* __restrict__ out)
{
    __shared__ char lbuf[2][33792];
    __shared__ float demod_l[128];

    int bid = blockIdx.x;
    int rt = bid & 31, mt = (bid >> 5) & 1, b = bid >> 6;
    int h0 = rt * 2;
    int t = threadIdx.x;
    int w = t >> 6, lane = t & 63;
    int mw = w & 1, rr = w >> 1;
    int lcol = lane & 15, kg = lane >> 4;

    if (t < 128) demod_l[t] = demod[b * 256 + mt * 128 + t];

    const unsigned short* xb = xst + (size_t)b * SPP * 256;

    // per-thread staging source pointers (kc=0 base); XOR pre-swizzled on the
    // GLOBAL side so LDS writes stay linear (ds_write_b128 conflict-free) and
    // swizzled ds_read_b128 is conflict-free.
    const unsigned short* sbase[9];
#pragma unroll
    for (int it = 0; it < 9; it++) {
        int pb = t + it * 256;
        const unsigned short* s = zeropad;
        if (pb < 2112) {
            int slot = pb >> 3, op = pb & 7;
            int row = slot / 66, col = slot - row * 66;
            int o = op ^ (slot & 7);
            int gh = h0 + row - 1, gw = col - 1;
            if ((unsigned)gh < 64u && (unsigned)gw < 64u)
                s = xb + ((size_t)(gh * 64 + gw)) * 256 + o * 8;
        }
        sbase[it] = s;
    }

    uint4 preg[9];
    // prologue: stage chunk 0
#pragma unroll
    for (int it = 0; it < 9; it++)
        if (it < 8 || t < 64) preg[it] = *(const uint4*)(sbase[it]);
#pragma unroll
    for (int it = 0; it < 9; it++)
        if (it < 8 || t < 64) *(uint4*)(&lbuf[0][0] + (size_t)(t + it * 256) * 16) = preg[it];
    __syncthreads();

    f32x4 acc[4][4];
#pragma unroll
    for (int m = 0; m < 4; m++)
#pragma unroll
        for (int n = 0; n < 4; n++) acc[m][n] = (f32x4){0.f, 0.f, 0.f, 0.f};

    int cob = mt * 128 + mw * 64;
    int base0 = rr * 66 + lcol;
    int cur = 0;

    for (int kc = 0; kc < 4; kc++) {
        const char* lb = &lbuf[0][0] + cur * 33792;
        char* lbn = &lbuf[0][0] + (cur ^ 1) * 33792;
        bool pf = kc < 3;
        if (pf) {
#pragma unroll
            for (int it = 0; it < 9; it++)
                if (it < 8 || t < 64) preg[it] = *(const uint4*)(sbase[it] + (kc + 1) * 64);
        }

#pragma unroll
        for (int tap = 0; tap < 9; tap++) {
            int dh = tap / 3, dw = tap - dh * 3;
            int slotT = base0 + dh * 66 + dw;
            int xorT = (slotT & 7) << 4;
            const char* lbp = lb + (slotT << 7);
            const unsigned short* wl = wt2 + tap * 65536 + (size_t)(cob + lcol) * 256 + kc * 64 + kg * 8;
#pragma unroll
            for (int kk = 0; kk < 2; kk++) {
                short8 a0 = *(const short8*)(wl + kk * 32);
                short8 a1 = *(const short8*)(wl + 4096 + kk * 32);
                short8 a2 = *(const short8*)(wl + 8192 + kk * 32);
                short8 a3 = *(const short8*)(wl + 12288 + kk * 32);
                int xk = ((kk * 4 + kg) << 4) ^ xorT;
#pragma unroll
                for (int n = 0; n < 4; n++) {
                    short8 bv = *(const short8*)(lbp + xk + n * 2048);
                    acc[0][n] = __builtin_amdgcn_mfma_f32_16x16x32_bf16(a0, bv, acc[0][n], 0, 0, 0);
                    acc[1][n] = __builtin_amdgcn_mfma_f32_16x16x32_bf16(a1, bv, acc[1][n], 0, 0, 0);
                    acc[2][n] = __builtin_amdgcn_mfma_f32_16x16x32_bf16(a2, bv, acc[2][n], 0, 0, 0);
                    acc[3][n] = __builtin_amdgcn_mfma_f32_16x16x32_bf16(a3, bv, acc[3][n], 0, 0, 0);
                }
            }
        }

        if (pf) {
#pragma unroll
            for (int it = 0; it < 9; it++)
                if (it < 8 || t < 64) *(uint4*)(lbn + (size_t)(t + it * 256) * 16) = preg[it];
        }
        __syncthreads();
        cur ^= 1;
    }

    // epilogue: out = acc * conv_scale*demod[co] * sp[p]*dsp[b]
    float dspb = dsp[b];
    int hout = h0 + rr;
    float spn[4];
#pragma unroll
    for (int n = 0; n < 4; n++)
        spn[n] = sp[b * SPP + hout * 64 + n * 16 + lcol] * dspb;

    // NOTE: co_l already contains mw*64; obase must NOT (round-2 OOB bug).
    size_t obase = ((size_t)(b * 256 + mt * 128)) * SPP + hout * 64 + lcol;
#pragma unroll
    for (int m = 0; m < 4; m++) {
#pragma unroll
        for (int r2 = 0; r2 < 4; r2++) {
            int co_l = mw * 64 + m * 16 + kg * 4 + r2;
            float dm = demod_l[co_l] * CONV_SCALE;
#pragma unroll
            for (int n = 0; n < 4; n++)
                out[obase + (size_t)co_l * SPP + n * 16] = acc[m][n][r2] * dm * spn[n];
        }
    }
}

// ---------------- fp32 fallback conv (round-1, known-good) ----------------

#define COTILE 16
#define TS 32
#define HALO 34
#define XS 36

__global__ __launch_bounds__(256) void k_conv_f32(
    const float* __restrict__ x, const float* __restrict__ weight,
    const float* __restrict__ style, const float* __restrict__ demod,
    const float* __restrict__ sp, const float* __restrict__ dsp,
    float* __restrict__ out) {
    __shared__ float xt[HALO * XS];
    __shared__ float wl[COTILE * 12];
    __shared__ float dml[COTILE];

    int bid = blockIdx.x;
    int tile = bid & 3;
    int cot = (bid >> 2) & 15;
    int b = bid >> 6;
    int h0 = (tile >> 1) * TS, w0 = (tile & 1) * TS;
    int t = threadIdx.x;
    int r = t >> 3;
    int cb = (t & 7) * 4;

    if (t < COTILE) dml[t] = demod[b * COUT + cot * COTILE + t];

    float acc[COTILE][4];
#pragma unroll
    for (int co = 0; co < COTILE; co++)
#pragma unroll
        for (int c = 0; c < 4; c++) acc[co][c] = 0.f;

    const float* xb = x + (size_t)b * CIN * SPP;
    const float* stb = style + b * CIN;

    for (int ci = 0; ci < CIN; ci++) {
        __syncthreads();
        const float* xc = xb + ci * SPP;
        for (int idx = t; idx < HALO * HALO; idx += 256) {
            int i = idx / HALO, j = idx - i * HALO;
            int h = h0 + i - 1, wv2 = w0 + j - 1;
            float v = 0.f;
            if ((unsigned)h < SPD && (unsigned)wv2 < SPD) v = xc[h * SPD + wv2];
            xt[i * XS + j] = v;
        }
        if (t < COTILE * 9) {
            int co = t / 9, tap = t - co * 9;
            float wv = weight[((cot * COTILE + co) * CIN + ci) * 9 + tap];
            wl[co * 12 + tap] = wv * (CONV_SCALE * stb[ci]) * dml[co];
        }
        __syncthreads();

        float xv[3][6];
#pragma unroll
        for (int dh = 0; dh < 3; dh++)
#pragma unroll
            for (int jj = 0; jj < 6; jj++)
                xv[dh][jj] = xt[(r + dh) * XS + cb + jj];

#pragma unroll
        for (int co = 0; co < COTILE; co++) {
            float w9[9];
#pragma unroll
            for (int q = 0; q < 9; q++) w9[q] = wl[co * 12 + q];
#pragma unroll
            for (int c = 0; c < 4; c++) {
                float a = acc[co][c];
#pragma unroll
                for (int dh = 0; dh < 3; dh++)
#pragma unroll
                    for (int dw = 0; dw < 3; dw++)
                        a += w9[dh * 3 + dw] * xv[dh][c + dw];
                acc[co][c] = a;
            }
        }
    }

    float dspb = dsp[b];
    int hh = h0 + r, ww = w0 + cb;
    const float* spb = sp + b * SPP + hh * SPD + ww;
    float m[4];
#pragma unroll
    for (int c = 0; c < 4; c++) m[c] = spb[c] * dspb;
#pragma unroll
    for (int co = 0; co < COTILE; co++) {
        float4 v = make_float4(acc[co][0] * m[0], acc[co][1] * m[1],
                               acc[co][2] * m[2], acc[co][3] * m[3]);
        *(float4*)&out[(size_t)((b * COUT + cot * COTILE + co) * SPP) + hh * SPD + ww] = v;
    }
}

// ---------------- launcher ----------------

extern "C" void kernel_launch(void* const* d_in, const int* in_sizes, int n_in,
                              void* d_out, int out_size, void* d_ws, size_t ws_size,
                              hipStream_t stream) {
    const float* x        = (const float*)d_in[0];
    const float* style_in = (const float*)d_in[1];
    const float* weight   = (const float*)d_in[2];
    const float* mod_w    = (const float*)d_in[3];
    const float* mod_b    = (const float*)d_in[4];
    const float* sp_w     = (const float*)d_in[5];
    const float* sp_b     = (const float*)d_in[6];
    float* out = (float*)d_out;
    char* wsb = (char*)d_ws;

    float* style = (float*)(wsb + WSB_STYLE);
    float* demod = (float*)(wsb + WSB_DEMOD);
    float* wsq   = (float*)(wsb + WSB_WSQ);
    float* sp    = (float*)(wsb + WSB_SP);
    float* dsp   = (float*)(wsb + WSB_DSP);
    unsigned short* wt2 = (unsigned short*)(wsb + WSB_WT2);
    unsigned short* xst = (unsigned short*)(wsb + WSB_XST);

    hipLaunchKernelGGL(k_zero, dim3(1), dim3(256), 0, stream, (unsigned*)(wsb + WSB_ZERO));
    hipLaunchKernelGGL(k_wsq, dim3(COUT), dim3(CIN), 0, stream, weight, wsq);
    hipLaunchKernelGGL(k_style, dim3(BB), dim3(256), 0, stream,
                       style_in, mod_w, mod_b, wsq, style, demod);
    hipLaunchKernelGGL(k_spatial, dim3(BB), dim3(256), 0, stream,
                       style_in, sp_w, sp_b, sp, dsp);

    if (ws_size >= WS_NEED) {
        hipLaunchKernelGGL(k_wt, dim3(2304), dim3(256), 0, stream, weight, wt2);
        hipLaunchKernelGGL(k_xt, dim3(512), dim3(128), 0, stream, x, style, xst);
        hipLaunchKernelGGL(k_conv_mfma, dim3(2048), dim3(256), 0, stream,
                           xst, wt2, demod, sp, dsp,
                           (const unsigned short*)(wsb + WSB_ZERO), out);
    } else {
        hipLaunchKernelGGL(k_conv_f32, dim3(2048), dim3(256), 0, stream,
                           x, weight, style, demod, sp, dsp, out);
    }
}

// Round 4
// 555.082 us; speedup vs baseline: 4.3425x; 1.0669x over previous
//
#include <hip/hip_runtime.h>
#include <math.h>

typedef short short8 __attribute__((ext_vector_type(8)));
typedef float f32x4 __attribute__((ext_vector_type(4)));

#define BB 32
#define CIN 256
#define COUT 256
#define SPD 64
#define SPP 4096
#define SDIM 256

constexpr float LIN_SCALE  = 0.0625f;                 // 1/sqrt(256)
constexpr float CONV_SCALE = 0.020833333333333332f;   // 1/sqrt(2304)
constexpr float EPS = 1e-6f;

// ---- ws byte-offset layout ----
#define WSB_STYLE   0ULL
#define WSB_DEMOD   32768ULL
#define WSB_WSQ     65536ULL
#define WSB_SP      327680ULL
#define WSB_DSP     851968ULL
#define WSB_ZERO    852096ULL      // 1 KiB of zeros
#define WSB_WT2     860160ULL      // 1,179,648 B bf16 weights [tap][co][ci]
#define WSB_XST     2097152ULL     // 67,108,864 B bf16 xs_t [b][p][ci]
#define WS_NEED     (WSB_XST + 67108864ULL)

__device__ inline unsigned short f2bf(float f) {
    unsigned u = __builtin_bit_cast(unsigned, f);
    u = (u + 0x7fffu + ((u >> 16) & 1u)) >> 16;   // RNE
    return (unsigned short)u;
}

// ---------------- prep kernels ----------------

__global__ void k_zero(unsigned* __restrict__ p) {
    p[threadIdx.x] = 0u;   // 256 u32 = 1 KiB
}

__global__ void k_wsq(const float* __restrict__ weight, float* __restrict__ wsq) {
    int co = blockIdx.x, ci = threadIdx.x;
    const float* wp = weight + (co * CIN + ci) * 9;
    float s = 0.f;
#pragma unroll
    for (int t = 0; t < 9; t++) { float v = wp[t]; s += v * v; }
    wsq[co * CIN + ci] = s;
}

__global__ void k_style(const float* __restrict__ style_in,
                        const float* __restrict__ mod_w,
                        const float* __restrict__ mod_b,
                        const float* __restrict__ wsq,
                        float* __restrict__ style,
                        float* __restrict__ demod) {
    __shared__ float s_in[SDIM];
    __shared__ float s2[CIN];
    int b = blockIdx.x, t = threadIdx.x;
    s_in[t] = style_in[b * 512 + t];
    __syncthreads();
    const float* mw = mod_w + t * SDIM;
    float acc = 0.f;
    for (int k = 0; k < SDIM; k++) acc += s_in[k] * mw[k];
    float st = acc * LIN_SCALE + mod_b[t];
    style[b * CIN + t] = st;
    s2[t] = st * st;
    __syncthreads();
    const float* wq = wsq + t * CIN;
    float d = 0.f;
    for (int ci = 0; ci < CIN; ci++) d += wq[ci] * s2[ci];
    demod[b * COUT + t] = rsqrtf(CONV_SCALE * CONV_SCALE * d + EPS);
}

__global__ void k_spatial(const float* __restrict__ style_in,
                          const float* __restrict__ sp_w,
                          const float* __restrict__ sp_b,
                          float* __restrict__ sp,
                          float* __restrict__ dsp) {
    __shared__ float s_in[SDIM];
    __shared__ float red[256];
    int b = blockIdx.x, t = threadIdx.x;
    s_in[t] = style_in[b * 512 + 256 + t];
    __syncthreads();
    float ss = 0.f;
    for (int i = 0; i < 16; i++) {
        int p = i * 256 + t;
        const float* wr = sp_w + p * SDIM;
        float acc = 0.f;
        for (int k = 0; k < SDIM; k++) acc += s_in[k] * wr[k];
        float v = acc * LIN_SCALE + sp_b[p];
        sp[b * SPP + p] = v;
        ss += v * v;
    }
    red[t] = ss; __syncthreads();
    for (int o = 128; o > 0; o >>= 1) { if (t < o) red[t] += red[t + o]; __syncthreads(); }
    if (t == 0) dsp[b] = sqrtf((float)SPP / red[0] + EPS);
}

// weight [co][ci][tap] fp32 -> wt2[tap][co][ci] bf16 (raw, unscaled)
__global__ void k_wt(const float* __restrict__ weight, unsigned short* __restrict__ wt2) {
    int idx = blockIdx.x * 256 + threadIdx.x;   // grid 2304 -> 589824
    int tap = idx >> 16;
    int r = idx & 65535;
    int co = r >> 8, ci = r & 255;
    wt2[idx] = f2bf(weight[(co * 256 + ci) * 9 + tap]);
}

// x [b][ci][p] fp32 -> xs_t[b][p][ci] bf16, scaled by style[b][ci]
// bid mapping puts b on XCD (b>>2) so xst[b] is produced in that XCD's L2.
__global__ void k_xt(const float* __restrict__ x, const float* __restrict__ style,
                     unsigned short* __restrict__ xst) {
    int bid = blockIdx.x;                 // 512 blocks
    int xcd = bid & 7;
    int b   = xcd * 4 + ((bid >> 3) & 3);
    int pc  = bid >> 5;                   // 0..15
    int t = threadIdx.x;                  // 0..127, ci pair = 2t
    int ci = t * 2;
    float s0 = style[b * 256 + ci], s1 = style[b * 256 + ci + 1];
    const float* xa = x + ((size_t)(b * 256 + ci)) * SPP + pc * 256;
    const float* xc = xa + SPP;
    unsigned* o = (unsigned*)(xst + ((size_t)b * SPP + pc * 256) * 256);
    for (int j = 0; j < 64; j++) {
        float4 a4 = *(const float4*)(xa + j * 4);
        float4 b4 = *(const float4*)(xc + j * 4);
        o[(j * 4 + 0) * 128 + t] = (unsigned)f2bf(a4.x * s0) | ((unsigned)f2bf(b4.x * s1) << 16);
        o[(j * 4 + 1) * 128 + t] = (unsigned)f2bf(a4.y * s0) | ((unsigned)f2bf(b4.y * s1) << 16);
        o[(j * 4 + 2) * 128 + t] = (unsigned)f2bf(a4.z * s0) | ((unsigned)f2bf(b4.z * s1) << 16);
        o[(j * 4 + 3) * 128 + t] = (unsigned)f2bf(a4.w * s0) | ((unsigned)f2bf(b4.w * s1) << 16);
    }
}

// ---------------- MFMA conv kernel (KC=32, 4 blocks/CU) ----------------
// bid bits: [phase(2)][rt(5)][mt(1)][xcd(3)]  -> b = xcd*4+phase (b clustered per XCD)
// block 256 = 4 waves: wave w: mw=w&1 (64-co half), rr=w>>1 (row in pair)
// LDS x-tile per K-chunk: 264 slots (4 rows x 66 cols) x 64B (32 ci bf16),
// chunk swizzle: byte off (kg ^ ((slot>>1)&3))*16, pre-applied to global src.

__global__ __launch_bounds__(256, 4) void k_conv_mfma(
    const unsigned short* __restrict__ xst,
    const unsigned short* __restrict__ wt2,
    const float* __restrict__ demod,
    const float* __restrict__ sp,
    const float* __restrict__ dsp,
    const unsigned short* __restrict__ zeropad,
    float* __restrict__ out)
{
    __shared__ union {
        char stage[2][16896];      // 2 x 264 slots x 64B
        float ep[4][2176];         // 4 waves x 32 rows x 68 floats (padded)
    } lds;
    __shared__ float demod_l[128];

    int bid = blockIdx.x;
    int xcd = bid & 7;
    int mt  = (bid >> 3) & 1;
    int rt  = (bid >> 4) & 31;
    int b   = xcd * 4 + (bid >> 9);
    int h0 = rt * 2;
    int t = threadIdx.x;
    int w = t >> 6, lane = t & 63;
    int mw = w & 1, rr = w >> 1;
    int lcol = lane & 15, kg = lane >> 4;

    if (t < 128) demod_l[t] = demod[b * 256 + mt * 128 + t];

    const unsigned short* xb = xst + (size_t)b * SPP * 256;

    // per-thread staging source pointers (kc advances source by 32 elements)
    const unsigned short* sbase[5];
#pragma unroll
    for (int it = 0; it < 5; it++) {
        int idx16 = t + it * 256;              // 16B-unit index, valid < 1056
        const unsigned short* s = zeropad;
        if (idx16 < 1056) {
            int slot = idx16 >> 2, j = idx16 & 3;
            int row = slot / 66, col = slot - row * 66;
            int g = j ^ ((slot >> 1) & 3);     // inverse swizzle on source
            int gh = h0 + row - 1, gw = col - 1;
            if ((unsigned)gh < 64u && (unsigned)gw < 64u)
                s = xb + ((size_t)(gh * 64 + gw)) * 256 + g * 8;
        }
        sbase[it] = s;
    }

    uint4 preg[5];
#define STAGE_LOAD(KC) { _Pragma("unroll") \
    for (int it = 0; it < 5; it++) \
        if (it < 4 || t < 32) preg[it] = *(const uint4*)(sbase[it] + (KC) * 32); }
#define STAGE_WRITE(BUF) { _Pragma("unroll") \
    for (int it = 0; it < 5; it++) \
        if (it < 4 || t < 32) *(uint4*)(&lds.stage[BUF][0] + (size_t)(t + it * 256) * 16) = preg[it]; }

    STAGE_LOAD(0);
    STAGE_WRITE(0);
    __syncthreads();

    f32x4 acc[4][4];
#pragma unroll
    for (int m = 0; m < 4; m++)
#pragma unroll
        for (int n = 0; n < 4; n++) acc[m][n] = (f32x4){0.f, 0.f, 0.f, 0.f};

    int cob = mt * 128 + mw * 64;
    int cur = 0;

    for (int kc = 0; kc < 8; kc++) {
        if (kc < 7) STAGE_LOAD(kc + 1);
        const char* lb = &lds.stage[cur][0];

#pragma unroll
        for (int tap = 0; tap < 9; tap++) {
            int dh = tap / 3, dw = tap - dh * 3;
            const unsigned short* wl = wt2 + tap * 65536 + (size_t)(cob + lcol) * 256 + kc * 32 + kg * 8;
            short8 a0 = *(const short8*)(wl);
            short8 a1 = *(const short8*)(wl + 4096);
            short8 a2 = *(const short8*)(wl + 8192);
            short8 a3 = *(const short8*)(wl + 12288);
            int sbase0 = (rr + dh) * 66 + dw + lcol;
            int q = (sbase0 >> 1) & 3;
            const char* lbp = lb + sbase0 * 64 + ((kg ^ q) << 4);
#pragma unroll
            for (int n = 0; n < 4; n++) {
                short8 bv = *(const short8*)(lbp + n * 1024);
                acc[0][n] = __builtin_amdgcn_mfma_f32_16x16x32_bf16(a0, bv, acc[0][n], 0, 0, 0);
                acc[1][n] = __builtin_amdgcn_mfma_f32_16x16x32_bf16(a1, bv, acc[1][n], 0, 0, 0);
                acc[2][n] = __builtin_amdgcn_mfma_f32_16x16x32_bf16(a2, bv, acc[2][n], 0, 0, 0);
                acc[3][n] = __builtin_amdgcn_mfma_f32_16x16x32_bf16(a3, bv, acc[3][n], 0, 0, 0);
            }
        }

        if (kc < 7) STAGE_WRITE(cur ^ 1);
        __syncthreads();
        cur ^= 1;
    }

    // ---- epilogue: scale, LDS transpose per wave, coalesced dwordx4 stores ----
    float dspb = dsp[b];
    int hout = h0 + rr;
    float spn[4];
#pragma unroll
    for (int n = 0; n < 4; n++)
        spn[n] = sp[b * SPP + hout * 64 + n * 16 + lcol] * dspb;

    float* ep = &lds.ep[w][0];
#pragma unroll
    for (int r = 0; r < 2; r++) {
        // write phase: rows lr = m2*16 + kg*4 + r2 (32 rows x 68-float stride)
#pragma unroll
        for (int m2 = 0; m2 < 2; m2++) {
            int m = r * 2 + m2;
#pragma unroll
            for (int r2 = 0; r2 < 4; r2++) {
                int lr = m2 * 16 + kg * 4 + r2;
                float dm = demod_l[mw * 64 + r * 32 + lr] * CONV_SCALE;
#pragma unroll
                for (int n = 0; n < 4; n++)
                    ep[lr * 68 + n * 16 + lcol] = acc[m][n][r2] * dm * spn[n];
            }
        }
        __syncthreads();
        // read+store phase: 8 instrs, each = 4 co rows x 64 contiguous floats
#pragma unroll
        for (int i = 0; i < 8; i++) {
            int lr = i * 4 + kg;
            f32x4 v = *(const f32x4*)(ep + lr * 68 + lcol * 4);
            int co_g = mw * 64 + r * 32 + lr;
            *(f32x4*)&out[((size_t)(b * 256 + mt * 128 + co_g)) * SPP + hout * 64 + lcol * 4] = v;
        }
        __syncthreads();
    }
}

// ---------------- fp32 fallback conv (round-1, known-good) ----------------

#define COTILE 16
#define TS 32
#define HALO 34
#define XS 36

__global__ __launch_bounds__(256) void k_conv_f32(
    const float* __restrict__ x, const float* __restrict__ weight,
    const float* __restrict__ style, const float* __restrict__ demod,
    const float* __restrict__ sp, const float* __restrict__ dsp,
    float* __restrict__ out) {
    __shared__ float xt[HALO * XS];
    __shared__ float wl[COTILE * 12];
    __shared__ float dml[COTILE];

    int bid = blockIdx.x;
    int tile = bid & 3;
    int cot = (bid >> 2) & 15;
    int b = bid >> 6;
    int h0 = (tile >> 1) * TS, w0 = (tile & 1) * TS;
    int t = threadIdx.x;
    int r = t >> 3;
    int cb = (t & 7) * 4;

    if (t < COTILE) dml[t] = demod[b * COUT + cot * COTILE + t];

    float acc[COTILE][4];
#pragma unroll
    for (int co = 0; co < COTILE; co++)
#pragma unroll
        for (int c = 0; c < 4; c++) acc[co][c] = 0.f;

    const float* xb = x + (size_t)b * CIN * SPP;
    const float* stb = style + b * CIN;

    for (int ci = 0; ci < CIN; ci++) {
        __syncthreads();
        const float* xc = xb + ci * SPP;
        for (int idx = t; idx < HALO * HALO; idx += 256) {
            int i = idx / HALO, j = idx - i * HALO;
            int h = h0 + i - 1, wv2 = w0 + j - 1;
            float v = 0.f;
            if ((unsigned)h < SPD && (unsigned)wv2 < SPD) v = xc[h * SPD + wv2];
            xt[i * XS + j] = v;
        }
        if (t < COTILE * 9) {
            int co = t / 9, tap = t - co * 9;
            float wv = weight[((cot * COTILE + co) * CIN + ci) * 9 + tap];
            wl[co * 12 + tap] = wv * (CONV_SCALE * stb[ci]) * dml[co];
        }
        __syncthreads();

        float xv[3][6];
#pragma unroll
        for (int dh = 0; dh < 3; dh++)
#pragma unroll
            for (int jj = 0; jj < 6; jj++)
                xv[dh][jj] = xt[(r + dh) * XS + cb + jj];

#pragma unroll
        for (int co = 0; co < COTILE; co++) {
            float w9[9];
#pragma unroll
            for (int q = 0; q < 9; q++) w9[q] = wl[co * 12 + q];
#pragma unroll
            for (int c = 0; c < 4; c++) {
                float a = acc[co][c];
#pragma unroll
                for (int dh = 0; dh < 3; dh++)
#pragma unroll
                    for (int dw = 0; dw < 3; dw++)
                        a += w9[dh * 3 + dw] * xv[dh][c + dw];
                acc[co][c] = a;
            }
        }
    }

    float dspb = dsp[b];
    int hh = h0 + r, ww = w0 + cb;
    const float* spb = sp + b * SPP + hh * SPD + ww;
    float m[4];
#pragma unroll
    for (int c = 0; c < 4; c++) m[c] = spb[c] * dspb;
#pragma unroll
    for (int co = 0; co < COTILE; co++) {
        float4 v = make_float4(acc[co][0] * m[0], acc[co][1] * m[1],
                               acc[co][2] * m[2], acc[co][3] * m[3]);
        *(float4*)&out[(size_t)((b * COUT + cot * COTILE + co) * SPP) + hh * SPD + ww] = v;
    }
}

// ---------------- launcher ----------------

extern "C" void kernel_launch(void* const* d_in, const int* in_sizes, int n_in,
                              void* d_out, int out_size, void* d_ws, size_t ws_size,
                              hipStream_t stream) {
    const float* x        = (const float*)d_in[0];
    const float* style_in = (const float*)d_in[1];
    const float* weight   = (const float*)d_in[2];
    const float* mod_w    = (const float*)d_in[3];
    const float* mod_b    = (const float*)d_in[4];
    const float* sp_w     = (const float*)d_in[5];
    const float* sp_b     = (const float*)d_in[6];
    float* out = (float*)d_out;
    char* wsb = (char*)d_ws;

    float* style = (float*)(wsb + WSB_STYLE);
    float* demod = (float*)(wsb + WSB_DEMOD);
    float* wsq   = (float*)(wsb + WSB_WSQ);
    float* sp    = (float*)(wsb + WSB_SP);
    float* dsp   = (float*)(wsb + WSB_DSP);
    unsigned short* wt2 = (unsigned short*)(wsb + WSB_WT2);
    unsigned short* xst = (unsigned short*)(wsb + WSB_XST);

    hipLaunchKernelGGL(k_zero, dim3(1), dim3(256), 0, stream, (unsigned*)(wsb + WSB_ZERO));
    hipLaunchKernelGGL(k_wsq, dim3(COUT), dim3(CIN), 0, stream, weight, wsq);
    hipLaunchKernelGGL(k_style, dim3(BB), dim3(256), 0, stream,
                       style_in, mod_w, mod_b, wsq, style, demod);
    hipLaunchKernelGGL(k_spatial, dim3(BB), dim3(256), 0, stream,
                       style_in, sp_w, sp_b, sp, dsp);

    if (ws_size >= WS_NEED) {
        hipLaunchKernelGGL(k_wt, dim3(2304), dim3(256), 0, stream, weight, wt2);
        hipLaunchKernelGGL(k_xt, dim3(512), dim3(128), 0, stream, x, style, xst);
        hipLaunchKernelGGL(k_conv_mfma, dim3(2048), dim3(256), 0, stream,
                           xst, wt2, demod, sp, dsp,
                           (const unsigned short*)(wsb + WSB_ZERO), out);
    } else {
        hipLaunchKernelGGL(k_conv_f32, dim3(2048), dim3(256), 0, stream,
                           x, weight, style, demod, sp, dsp, out);
    }
}

// Round 5
// 506.583 us; speedup vs baseline: 4.7583x; 1.0957x over previous
//
#include <hip/hip_runtime.h>
#include <math.h>

typedef short short8 __attribute__((ext_vector_type(8)));
typedef float f32x4 __attribute__((ext_vector_type(4)));

#define BB 32
#define CIN 256
#define COUT 256
#define SPD 64
#define SPP 4096
#define SDIM 256

constexpr float LIN_SCALE  = 0.0625f;                 // 1/sqrt(256)
constexpr float CONV_SCALE = 0.020833333333333332f;   // 1/sqrt(2304)
constexpr float EPS = 1e-6f;

// ---- ws byte-offset layout ----
#define WSB_STYLE   0ULL
#define WSB_DEMOD   32768ULL
#define WSB_WSQ     65536ULL
#define WSB_SP      327680ULL
#define WSB_DSP     851968ULL
#define WSB_ZERO    852096ULL      // 1 KiB of zeros
#define WSB_WT2     860160ULL      // 1,179,648 B bf16 weights [tap][co][ci]
#define WSB_XST     2097152ULL     // 67,108,864 B bf16 xs_t [b][p][ci]
#define WS_NEED     (WSB_XST + 67108864ULL)

__device__ inline unsigned short f2bf(float f) {
    unsigned u = __builtin_bit_cast(unsigned, f);
    u = (u + 0x7fffu + ((u >> 16) & 1u)) >> 16;   // RNE
    return (unsigned short)u;
}

// async global->LDS DMA, 16B per lane; LDS dest = wave-uniform base + lane*16
__device__ inline void dma16(const void* g, void* l) {
    __builtin_amdgcn_global_load_lds(
        (const __attribute__((address_space(1))) unsigned int*)g,
        (__attribute__((address_space(3))) unsigned int*)l, 16, 0, 0);
}

// ---------------- prep kernels ----------------

__global__ void k_zero(unsigned* __restrict__ p) {
    p[threadIdx.x] = 0u;   // 256 u32 = 1 KiB
}

__global__ void k_wsq(const float* __restrict__ weight, float* __restrict__ wsq) {
    int co = blockIdx.x, ci = threadIdx.x;
    const float* wp = weight + (co * CIN + ci) * 9;
    float s = 0.f;
#pragma unroll
    for (int t = 0; t < 9; t++) { float v = wp[t]; s += v * v; }
    wsq[co * CIN + ci] = s;
}

__global__ void k_style(const float* __restrict__ style_in,
                        const float* __restrict__ mod_w,
                        const float* __restrict__ mod_b,
                        const float* __restrict__ wsq,
                        float* __restrict__ style,
                        float* __restrict__ demod) {
    __shared__ float s_in[SDIM];
    __shared__ float s2[CIN];
    int b = blockIdx.x, t = threadIdx.x;
    s_in[t] = style_in[b * 512 + t];
    __syncthreads();
    const float* mw = mod_w + t * SDIM;
    float acc = 0.f;
    for (int k = 0; k < SDIM; k++) acc += s_in[k] * mw[k];
    float st = acc * LIN_SCALE + mod_b[t];
    style[b * CIN + t] = st;
    s2[t] = st * st;
    __syncthreads();
    const float* wq = wsq + t * CIN;
    float d = 0.f;
    for (int ci = 0; ci < CIN; ci++) d += wq[ci] * s2[ci];
    demod[b * COUT + t] = rsqrtf(CONV_SCALE * CONV_SCALE * d + EPS);
}

__global__ void k_spatial(const float* __restrict__ style_in,
                          const float* __restrict__ sp_w,
                          const float* __restrict__ sp_b,
                          float* __restrict__ sp,
                          float* __restrict__ dsp) {
    __shared__ float s_in[SDIM];
    __shared__ float red[256];
    int b = blockIdx.x, t = threadIdx.x;
    s_in[t] = style_in[b * 512 + 256 + t];
    __syncthreads();
    float ss = 0.f;
    for (int i = 0; i < 16; i++) {
        int p = i * 256 + t;
        const float* wr = sp_w + p * SDIM;
        float acc = 0.f;
        for (int k = 0; k < SDIM; k++) acc += s_in[k] * wr[k];
        float v = acc * LIN_SCALE + sp_b[p];
        sp[b * SPP + p] = v;
        ss += v * v;
    }
    red[t] = ss; __syncthreads();
    for (int o = 128; o > 0; o >>= 1) { if (t < o) red[t] += red[t + o]; __syncthreads(); }
    if (t == 0) dsp[b] = sqrtf((float)SPP / red[0] + EPS);
}

// weight [co][ci][tap] fp32 -> wt2[tap][co][ci] bf16 (raw, unscaled)
__global__ void k_wt(const float* __restrict__ weight, unsigned short* __restrict__ wt2) {
    int idx = blockIdx.x * 256 + threadIdx.x;   // grid 2304 -> 589824
    int tap = idx >> 16;
    int r = idx & 65535;
    int co = r >> 8, ci = r & 255;
    wt2[idx] = f2bf(weight[(co * 256 + ci) * 9 + tap]);
}

// x [b][ci][p] fp32 -> xs_t[b][p][ci] bf16, scaled by style[b][ci]
__global__ void k_xt(const float* __restrict__ x, const float* __restrict__ style,
                     unsigned short* __restrict__ xst) {
    int bid = blockIdx.x;                 // 512 blocks
    int xcd = bid & 7;
    int b   = xcd * 4 + ((bid >> 3) & 3);
    int pc  = bid >> 5;                   // 0..15
    int t = threadIdx.x;                  // 0..127, ci pair = 2t
    int ci = t * 2;
    float s0 = style[b * 256 + ci], s1 = style[b * 256 + ci + 1];
    const float* xa = x + ((size_t)(b * 256 + ci)) * SPP + pc * 256;
    const float* xc = xa + SPP;
    unsigned* o = (unsigned*)(xst + ((size_t)b * SPP + pc * 256) * 256);
    for (int j = 0; j < 64; j++) {
        float4 a4 = *(const float4*)(xa + j * 4);
        float4 b4 = *(const float4*)(xc + j * 4);
        o[(j * 4 + 0) * 128 + t] = (unsigned)f2bf(a4.x * s0) | ((unsigned)f2bf(b4.x * s1) << 16);
        o[(j * 4 + 1) * 128 + t] = (unsigned)f2bf(a4.y * s0) | ((unsigned)f2bf(b4.y * s1) << 16);
        o[(j * 4 + 2) * 128 + t] = (unsigned)f2bf(a4.z * s0) | ((unsigned)f2bf(b4.z * s1) << 16);
        o[(j * 4 + 3) * 128 + t] = (unsigned)f2bf(a4.w * s0) | ((unsigned)f2bf(b4.w * s1) << 16);
    }
}

// ---------------- MFMA conv kernel (KC=32, DMA staging, 4 blocks/CU) ----------------
// bid bits: [phase(2)][rt(5)][mt(1)][xcd(3)]  -> b = xcd*4+phase
// block 256 = 4 waves: wave w: mw=w&1 (64-co half), rr=w>>1 (row in pair)
// LDS x-tile per K-chunk: 264 slots (4 rows x 66 cols) x 64B (32 ci bf16),
// staged via global_load_lds: linear LDS dest, inverse-swizzled global src,
// swizzled ds_read. Buffer 1088 16B-units (64-unit slack for the tail call).

__global__ __launch_bounds__(256, 4) void k_conv_mfma(
    const unsigned short* __restrict__ xst,
    const unsigned short* __restrict__ wt2,
    const float* __restrict__ demod,
    const float* __restrict__ sp,
    const float* __restrict__ dsp,
    const unsigned short* __restrict__ zeropad,
    float* __restrict__ out)
{
    __shared__ union {
        char stage[2][17408];      // 2 x 1088 units x 16B
        float ep[4][2176];         // 4 waves x 32 rows x 68 floats (= 34816 B)
    } lds;
    __shared__ float demod_l[128];

    int bid = blockIdx.x;
    int xcd = bid & 7;
    int mt  = (bid >> 3) & 1;
    int rt  = (bid >> 4) & 31;
    int b   = xcd * 4 + (bid >> 9);
    int h0 = rt * 2;
    int t = threadIdx.x;
    int w = t >> 6, lane = t & 63;
    int mw = w & 1, rr = w >> 1;
    int lcol = lane & 15, kg = lane >> 4;

    if (t < 128) demod_l[t] = demod[b * 256 + mt * 128 + t];

    const unsigned short* xb = xst + (size_t)b * SPP * 256;

    // per-thread DMA source pointers (kc advances source by 32 elements).
    // idx16 in [0,1056) maps to a real (slot, 16B-quarter); others read zeros.
    const unsigned short* sbase[5];
#pragma unroll
    for (int it = 0; it < 5; it++) {
        int idx16 = t + it * 256;
        const unsigned short* s = zeropad;
        if (idx16 < 1056) {
            int slot = idx16 >> 2, j = idx16 & 3;
            int row = slot / 66, col = slot - row * 66;
            int g = j ^ ((slot >> 1) & 3);     // inverse swizzle on source
            int gh = h0 + row - 1, gw = col - 1;
            if ((unsigned)gh < 64u && (unsigned)gw < 64u)
                s = xb + ((size_t)(gh * 64 + gw)) * 256 + g * 8;
        }
        sbase[it] = s;
    }

    // DMA one K-chunk into buffer BUF; it=4 tail issued by wave 0 only
    // (dest units 1024..1087 stay inside the 1088-unit buffer).
#define STAGE_DMA(BUF, KC) { _Pragma("unroll") \
    for (int it = 0; it < 4; it++) \
        dma16(sbase[it] + (KC) * 32, &lds.stage[BUF][0] + (t + it * 256) * 16); \
    if (t < 64) dma16(sbase[4] + (KC) * 32, &lds.stage[BUF][0] + (t + 1024) * 16); }

    STAGE_DMA(0, 0);

    f32x4 acc[4][4];
#pragma unroll
    for (int m = 0; m < 4; m++)
#pragma unroll
        for (int n = 0; n < 4; n++) acc[m][n] = (f32x4){0.f, 0.f, 0.f, 0.f};

    int cob = mt * 128 + mw * 64;
    int cur = 0;
    __syncthreads();   // vmcnt(0) drain of prologue DMA + barrier

    for (int kc = 0; kc < 8; kc++) {
        if (kc < 7) STAGE_DMA(cur ^ 1, kc + 1);   // lands during this kc's MFMAs
        const char* lb = &lds.stage[cur][0];

#pragma unroll
        for (int tap = 0; tap < 9; tap++) {
            int dh = tap / 3, dw = tap - dh * 3;
            const unsigned short* wl = wt2 + tap * 65536 + (size_t)(cob + lcol) * 256 + kc * 32 + kg * 8;
            short8 a0 = *(const short8*)(wl);
            short8 a1 = *(const short8*)(wl + 4096);
            short8 a2 = *(const short8*)(wl + 8192);
            short8 a3 = *(const short8*)(wl + 12288);
            int sbase0 = (rr + dh) * 66 + dw + lcol;
            int q = (sbase0 >> 1) & 3;
            const char* lbp = lb + sbase0 * 64 + ((kg ^ q) << 4);
#pragma unroll
            for (int n = 0; n < 4; n++) {
                short8 bv = *(const short8*)(lbp + n * 1024);
                acc[0][n] = __builtin_amdgcn_mfma_f32_16x16x32_bf16(a0, bv, acc[0][n], 0, 0, 0);
                acc[1][n] = __builtin_amdgcn_mfma_f32_16x16x32_bf16(a1, bv, acc[1][n], 0, 0, 0);
                acc[2][n] = __builtin_amdgcn_mfma_f32_16x16x32_bf16(a2, bv, acc[2][n], 0, 0, 0);
                acc[3][n] = __builtin_amdgcn_mfma_f32_16x16x32_bf16(a3, bv, acc[3][n], 0, 0, 0);
            }
        }

        __syncthreads();   // implicit vmcnt(0): DMA landed long ago
        cur ^= 1;
    }

    // ---- epilogue: scale, LDS transpose per wave, coalesced dwordx4 stores ----
    float dspb = dsp[b];
    int hout = h0 + rr;
    float spn[4];
#pragma unroll
    for (int n = 0; n < 4; n++)
        spn[n] = sp[b * SPP + hout * 64 + n * 16 + lcol] * dspb;

    float* ep = &lds.ep[w][0];
#pragma unroll
    for (int r = 0; r < 2; r++) {
#pragma unroll
        for (int m2 = 0; m2 < 2; m2++) {
            int m = r * 2 + m2;
#pragma unroll
            for (int r2 = 0; r2 < 4; r2++) {
                int lr = m2 * 16 + kg * 4 + r2;
                float dm = demod_l[mw * 64 + r * 32 + lr] * CONV_SCALE;
#pragma unroll
                for (int n = 0; n < 4; n++)
                    ep[lr * 68 + n * 16 + lcol] = acc[m][n][r2] * dm * spn[n];
            }
        }
        __syncthreads();
#pragma unroll
        for (int i = 0; i < 8; i++) {
            int lr = i * 4 + kg;
            f32x4 v = *(const f32x4*)(ep + lr * 68 + lcol * 4);
            int co_g = mw * 64 + r * 32 + lr;
            *(f32x4*)&out[((size_t)(b * 256 + mt * 128 + co_g)) * SPP + hout * 64 + lcol * 4] = v;
        }
        __syncthreads();
    }
}

// ---------------- fp32 fallback conv (round-1, known-good) ----------------

#define COTILE 16
#define TS 32
#define HALO 34
#define XS 36

__global__ __launch_bounds__(256) void k_conv_f32(
    const float* __restrict__ x, const float* __restrict__ weight,
    const float* __restrict__ style, const float* __restrict__ demod,
    const float* __restrict__ sp, const float* __restrict__ dsp,
    float* __restrict__ out) {
    __shared__ float xt[HALO * XS];
    __shared__ float wl[COTILE * 12];
    __shared__ float dml[COTILE];

    int bid = blockIdx.x;
    int tile = bid & 3;
    int cot = (bid >> 2) & 15;
    int b = bid >> 6;
    int h0 = (tile >> 1) * TS, w0 = (tile & 1) * TS;
    int t = threadIdx.x;
    int r = t >> 3;
    int cb = (t & 7) * 4;

    if (t < COTILE) dml[t] = demod[b * COUT + cot * COTILE + t];

    float acc[COTILE][4];
#pragma unroll
    for (int co = 0; co < COTILE; co++)
#pragma unroll
        for (int c = 0; c < 4; c++) acc[co][c] = 0.f;

    const float* xb = x + (size_t)b * CIN * SPP;
    const float* stb = style + b * CIN;

    for (int ci = 0; ci < CIN; ci++) {
        __syncthreads();
        const float* xc = xb + ci * SPP;
        for (int idx = t; idx < HALO * HALO; idx += 256) {
            int i = idx / HALO, j = idx - i * HALO;
            int h = h0 + i - 1, wv2 = w0 + j - 1;
            float v = 0.f;
            if ((unsigned)h < SPD && (unsigned)wv2 < SPD) v = xc[h * SPD + wv2];
            xt[i * XS + j] = v;
        }
        if (t < COTILE * 9) {
            int co = t / 9, tap = t - co * 9;
            float wv = weight[((cot * COTILE + co) * CIN + ci) * 9 + tap];
            wl[co * 12 + tap] = wv * (CONV_SCALE * stb[ci]) * dml[co];
        }
        __syncthreads();

        float xv[3][6];
#pragma unroll
        for (int dh = 0; dh < 3; dh++)
#pragma unroll
            for (int jj = 0; jj < 6; jj++)
                xv[dh][jj] = xt[(r + dh) * XS + cb + jj];

#pragma unroll
        for (int co = 0; co < COTILE; co++) {
            float w9[9];
#pragma unroll
            for (int q = 0; q < 9; q++) w9[q] = wl[co * 12 + q];
#pragma unroll
            for (int c = 0; c < 4; c++) {
                float a = acc[co][c];
#pragma unroll
                for (int dh = 0; dh < 3; dh++)
#pragma unroll
                    for (int dw = 0; dw < 3; dw++)
                        a += w9[dh * 3 + dw] * xv[dh][c + dw];
                acc[co][c] = a;
            }
        }
    }

    float dspb = dsp[b];
    int hh = h0 + r, ww = w0 + cb;
    const float* spb = sp + b * SPP + hh * SPD + ww;
    float m[4];
#pragma unroll
    for (int c = 0; c < 4; c++) m[c] = spb[c] * dspb;
#pragma unroll
    for (int co = 0; co < COTILE; co++) {
        float4 v = make_float4(acc[co][0] * m[0], acc[co][1] * m[1],
                               acc[co][2] * m[2], acc[co][3] * m[3]);
        *(float4*)&out[(size_t)((b * COUT + cot * COTILE + co) * SPP) + hh * SPD + ww] = v;
    }
}

// ---------------- launcher ----------------

extern "C" void kernel_launch(void* const* d_in, const int* in_sizes, int n_in,
                              void* d_out, int out_size, void* d_ws, size_t ws_size,
                              hipStream_t stream) {
    const float* x        = (const float*)d_in[0];
    const float* style_in = (const float*)d_in[1];
    const float* weight   = (const float*)d_in[2];
    const float* mod_w    = (const float*)d_in[3];
    const float* mod_b    = (const float*)d_in[4];
    const float* sp_w     = (const float*)d_in[5];
    const float* sp_b     = (const float*)d_in[6];
    float* out = (float*)d_out;
    char* wsb = (char*)d_ws;

    float* style = (float*)(wsb + WSB_STYLE);
    float* demod = (float*)(wsb + WSB_DEMOD);
    float* wsq   = (float*)(wsb + WSB_WSQ);
    float* sp    = (float*)(wsb + WSB_SP);
    float* dsp   = (float*)(wsb + WSB_DSP);
    unsigned short* wt2 = (unsigned short*)(wsb + WSB_WT2);
    unsigned short* xst = (unsigned short*)(wsb + WSB_XST);

    hipLaunchKernelGGL(k_zero, dim3(1), dim3(256), 0, stream, (unsigned*)(wsb + WSB_ZERO));
    hipLaunchKernelGGL(k_wsq, dim3(COUT), dim3(CIN), 0, stream, weight, wsq);
    hipLaunchKernelGGL(k_style, dim3(BB), dim3(256), 0, stream,
                       style_in, mod_w, mod_b, wsq, style, demod);
    hipLaunchKernelGGL(k_spatial, dim3(BB), dim3(256), 0, stream,
                       style_in, sp_w, sp_b, sp, dsp);

    if (ws_size >= WS_NEED) {
        hipLaunchKernelGGL(k_wt, dim3(2304), dim3(256), 0, stream, weight, wt2);
        hipLaunchKernelGGL(k_xt, dim3(512), dim3(128), 0, stream, x, style, xst);
        hipLaunchKernelGGL(k_conv_mfma, dim3(2048), dim3(256), 0, stream,
                           xst, wt2, demod, sp, dsp,
                           (const unsigned short*)(wsb + WSB_ZERO), out);
    } else {
        hipLaunchKernelGGL(k_conv_f32, dim3(2048), dim3(256), 0, stream,
                           x, weight, style, demod, sp, dsp, out);
    }
}